// Round 12
// baseline (217.094 us; speedup 1.0000x reference)
//
#include <hip/hip_runtime.h>
#include <math.h>

// Sizes (fixed by the reference)
#define NB 1024
#define TT 5
#define NN 6
#define DD 192
#define EE 12
#define MM 12
#define LL 512
#define OO 6
#define GOUT 768              // GRU GEMM N: [r|z|inn|hn]
#define KPAD 224              // GRU K: 12 + 192 + 20 pad
#define NKT (KPAD/32)         // 7 k-tiles
#define NJT (GOUT/16)         // 48 n-tiles

#define ROWS 30               // (t,n) rows per batch
#define HP 196                // sh_h pitch (floats)
#define LNKPU 20              // linkA pitch (uints)
#define GRUPU 116             // gruA pitch (uints) = 464 B

typedef __attribute__((ext_vector_type(8))) _Float16 f16x8;
typedef __attribute__((ext_vector_type(2))) _Float16 h2;
typedef __attribute__((ext_vector_type(4))) float f32x4;

__device__ __forceinline__ float dot4(float4 a, float4 b) {
  return a.x*b.x + a.y*b.y + a.z*b.z + a.w*b.w;
}
__device__ __forceinline__ unsigned short f2h(float f) {
  _Float16 h = (_Float16)f;
  unsigned short s; __builtin_memcpy(&s, &h, 2); return s;
}
// pack two f32 -> fp16x2 in ONE instruction (v_cvt_pkrtz_f16_f32).
__device__ __forceinline__ unsigned int pkrtz(float a, float b) {
  auto v = __builtin_amdgcn_cvt_pkrtz(a, b);
  return __builtin_bit_cast(unsigned int, v);
}
// fast sigmoid / tanh (v_exp + v_rcp)
__device__ __forceinline__ float fsig(float x) {
  float e = __expf(-x);
  return __builtin_amdgcn_rcpf(1.f + e);
}
// tanh(x) = 2/(1+exp(-2x)) - 1
__device__ __forceinline__ float ftanh(float x) {
  float e = __expf(-2.f * x);
  return 2.f * __builtin_amdgcn_rcpf(1.f + e) - 1.f;
}

// ---------------------------------------------------------------- k_pack (GRU W, fp16)
__global__ void k_pack(const float* __restrict__ Wih, const float* __restrict__ Whh,
                       const float* __restrict__ bih, const float* __restrict__ bhh,
                       unsigned short* __restrict__ Bh, float* __restrict__ bias768)
{
  int idx = blockIdx.x * 256 + threadIdx.x;
  if (idx < GOUT) {
    int c = idx; float b;
    if (c < 384)      b = bih[c] + bhh[c];
    else if (c < 576) b = bih[c];
    else              b = bhh[c - 192];
    bias768[c] = b;
  }
  if (idx >= NJT*NKT*512) return;
  int e = idx & 7, l = (idx >> 3) & 63;
  int rem = idx >> 9, kt = rem % NKT, j = rem / NKT;
  int k = kt*32 + ((l >> 4) << 3) + e;
  int c = j*16 + (l & 15);
  float v = 0.f;
  if (k < 204) {
    if (c < 384)      v = (k < 12) ? Wih[c*MM + k] : Whh[(size_t)c*DD + (k-12)];
    else if (c < 576) v = (k < 12) ? Wih[c*MM + k] : 0.f;
    else              v = (k < 12) ? 0.f : Whh[(size_t)(c-192)*DD + (k-12)];
  }
  Bh[idx] = f2h(v);
}

// ---------------------------------------------------------------- k_pack_link (fp16)
// W1^T with b1 folded at k==12 (A supplies 1.0 there).
__global__ void k_pack_link(const float* __restrict__ w1, const float* __restrict__ b1,
                            unsigned short* __restrict__ BLh)
{
  int idx = blockIdx.x * 256 + threadIdx.x;
  if (idx >= 32*512) return;
  int e = idx & 7, l = (idx >> 3) & 63, nt = idx >> 9;
  int k = ((l >> 4) << 3) + e;
  int c = nt*16 + (l & 15);
  float v = 0.f;
  if (k < 12)       v = w1[c*EE + k];
  else if (k == 12) v = b1[c];
  BLh[idx] = f2h(v);
}

// ---------------------------------------------------------------- k_fused
// One WG per batch. LDS ~51KB. Link-MFMA and mh phases are SEPARATED by a
// barrier: merging them (round 9) overlapped the link accumulators with the
// mh unroll-8 load pipeline -> compiler spilled ~400B/thread to scratch
// (106MB fetch + 106MB write per dispatch). Barrier keeps pools sequential.
__global__ __launch_bounds__(256, 3)
void k_fused(const float* __restrict__ nr, const float* __restrict__ pos,
             const int* __restrict__ attmat,
             const unsigned short* __restrict__ BLh,
             const float* __restrict__ lw2, const float* __restrict__ lb2,
             const float* __restrict__ msg_Wh, const float* __restrict__ msg_We,
             const float* __restrict__ msg_b,
             const unsigned short* __restrict__ Bh, const float* __restrict__ bias768,
             const float* __restrict__ conv1_w, const float* __restrict__ conv1_b,
             const float* __restrict__ conv2_w, const float* __restrict__ conv2_b,
             float* __restrict__ out)
{
  __shared__ __align__(16) float sh_h[ROWS][HP];          // 23520 B fp32 state
  __shared__ __align__(16) unsigned int sh_e[180][6];     // 4320 B fp16x2 edge feats
  __shared__ __align__(16) unsigned int sh_m[180][6];     // 4320 B fp16x2 messages
  __shared__ __align__(16) float sh_mh[ROWS][MM];         // 1440 B
  __shared__ float sh_adj[192];                           // 768 B
  __shared__ float sh_w2[LL];                             // 2048 B
  __shared__ __align__(16) unsigned int sh_we[MM][6];     // 288 B fp16x2 msg_We
  __shared__ __align__(16) unsigned int shA[192*LNKPU];   // 15360 B (linkA|gruA)
  __shared__ float red[4][OO];

  const int tid = threadIdx.x;
  const int b = blockIdx.x;
  const int lane = tid & 63, wid = tid >> 6;
  const int col = lane & 15, quad = lane >> 4;

  // ---- Phase 0: h, edge feats (fp16), We (fp16), w2 ----
  for (int i = tid; i < TT*DD*NN; i += 256) {
    int t = i / (DD*NN), rem = i % (DD*NN);
    int d = rem / NN, n = rem % NN;
    sh_h[t*NN + n][d] = nr[(size_t)b*TT*DD*NN + i];       // coalesced
  }
  for (int idx = tid; idx < 180*6; idx += 256) {
    int e = idx / 6, p = idx % 6;
    int t = e / 36, ij = e % 36;
    int i_ = ij / NN, j_ = ij % NN;
    bool msk = (attmat[(b*TT + t)*36 + ij] == 1) && (i_ != j_);
    int srcn = (p < 3) ? i_ : j_;
    int c0   = (p < 3) ? 2*p : 2*p - 6;
    const float* pb = pos + (((size_t)(b*TT + t))*NN + srcn)*6;
    float a0 = msk ? pb[c0] : 0.f, a1 = msk ? pb[c0+1] : 0.f;
    sh_e[e][p] = pkrtz(a0, a1);
  }
  for (int idx = tid; idx < MM*6; idx += 256) {
    int o = idx / 6, p = idx % 6;
    sh_we[o][p] = pkrtz(msg_We[o*EE + 2*p], msg_We[o*EE + 2*p + 1]);
  }
  for (int i = tid; i < LL; i += 256) sh_w2[i] = lw2[i];
  __syncthreads();

  for (int L = 0; L < 2; ++L) {
    // ---- link A staging: pure fp16 copy (+1.0 at k=12 for b1 fold) ----
    for (int idx = tid; idx < 192*16; idx += 256) {
      int r = idx >> 4, p = idx & 15;
      unsigned int v = 0;
      if (r < 180) {
        if (p < 6)       v = (L == 0) ? sh_e[r][p] : sh_m[r][p];
        else if (p == 6) v = 0x00003C00u;   // (1.0h, 0)
      }
      shA[r*LNKPU + p] = v;
    }
    __syncthreads();

    // ---- link MFMA: wave owns m-tiles {wid*3..+2}; fused relu->w2->sigmoid ----
    {
      f16x8 am[3];
      #pragma unroll
      for (int mtl = 0; mtl < 3; ++mtl)
        am[mtl] = *(const f16x8*)((const char*)shA
                    + ((wid*3 + mtl)*16 + col)*(LNKPU*4) + quad*16);
      float s[3][4];
      #pragma unroll
      for (int mtl = 0; mtl < 3; ++mtl)
        #pragma unroll
        for (int q = 0; q < 4; ++q) s[mtl][q] = 0.f;
      for (int nt = 0; nt < 32; ++nt) {
        f16x8 bh = *(const f16x8*)(BLh + nt*512 + lane*8);
        float w2v = sh_w2[nt*16 + col];
        #pragma unroll
        for (int mtl = 0; mtl < 3; ++mtl) {
          f32x4 acc = (f32x4)0.f;
          acc = __builtin_amdgcn_mfma_f32_16x16x32_f16(am[mtl], bh, acc, 0, 0, 0);
          #pragma unroll
          for (int q = 0; q < 4; ++q)
            s[mtl][q] += w2v * fmaxf(acc[q], 0.f);   // b1 folded into acc
        }
      }
      #pragma unroll
      for (int mtl = 0; mtl < 3; ++mtl)
        #pragma unroll
        for (int q = 0; q < 4; ++q) {
          float v = s[mtl][q];
          v += __shfl_xor(v, 1); v += __shfl_xor(v, 2);
          v += __shfl_xor(v, 4); v += __shfl_xor(v, 8);
          s[mtl][q] = v;
        }
      if (col == 0) {
        float b2 = lb2[0];
        #pragma unroll
        for (int mtl = 0; mtl < 3; ++mtl)
          #pragma unroll
          for (int q = 0; q < 4; ++q)
            sh_adj[wid*48 + mtl*16 + quad*4 + q] = fsig(s[mtl][q] + b2);
      }
    }
    __syncthreads();   // fence: link register pool dies before mh pipeline

    // ---- mh[r][o] = msg_b[o] + Wh[o,:] . h[r,:] ----
    for (int idx = tid; idx < ROWS*MM; idx += 256) {
      int r = idx / MM, o = idx % MM;
      const float4* wrow = (const float4*)(msg_Wh + (size_t)o*DD);
      const float4* hrow = (const float4*)&sh_h[r][0];
      float acc = msg_b[o];
      #pragma unroll 8
      for (int d4 = 0; d4 < DD/4; ++d4) acc += dot4(wrow[d4], hrow[d4]);
      sh_mh[r][o] = acc;
    }
    __syncthreads();

    // ---- m = adj * relu(mh_j + We.e)  (half2 me, packed store) ----
    for (int idx = tid; idx < 180*6; idx += 256) {
      int e = idx / 6, op = idx % 6;
      int t = e / 36, j_ = e % 6;
      h2 a2 = {(_Float16)0.f, (_Float16)0.f};
      h2 b2 = {(_Float16)0.f, (_Float16)0.f};
      #pragma unroll
      for (int p = 0; p < 6; ++p) {
        h2 ev = __builtin_bit_cast(h2, sh_e[e][p]);
        a2 += __builtin_bit_cast(h2, sh_we[2*op][p]) * ev;
        b2 += __builtin_bit_cast(h2, sh_we[2*op+1][p]) * ev;
      }
      float me0 = (float)a2[0] + (float)a2[1];
      float me1 = (float)b2[0] + (float)b2[1];
      float mh0 = sh_mh[t*NN + j_][2*op];
      float mh1 = sh_mh[t*NN + j_][2*op+1];
      float adj = sh_adj[e];
      sh_m[e][op] = pkrtz(adj * fmaxf(mh0 + me0, 0.f),
                          adj * fmaxf(mh1 + me1, 0.f));
    }
    __syncthreads();

    // ---- GRU A staging (x-sums inline; h fp32->fp16) ----
    for (int idx = tid; idx < 32*(KPAD/2); idx += 256) {
      int r = idx / (KPAD/2), kp = idx % (KPAD/2);
      unsigned int v = 0;
      if (r < ROWS) {
        if (kp < 6) {            // k0,k1 < 12: msum over 6 source nodes
          int t = r / NN, i_ = r % NN;
          const unsigned int* mrow = &sh_m[t*36 + i_*NN][kp];
          float a0 = 0.f, a1 = 0.f;
          #pragma unroll
          for (int j = 0; j < 6; ++j) {
            h2 mv = __builtin_bit_cast(h2, mrow[j*6]);
            a0 += (float)mv[0]; a1 += (float)mv[1];
          }
          v = pkrtz(a0, a1);
        } else if (kp < 102) {   // h part
          float2 hv = *(const float2*)&sh_h[r][2*kp - 12];
          v = pkrtz(hv.x, hv.y);
        }
      }
      shA[r*GRUPU + kp] = v;
    }
    __syncthreads();

    // ---- GRU MFMA, one d-tile at a time (no spill) ----
    {
      const char* ahb = (const char*)shA + col*(GRUPU*4) + quad*16;
      #pragma unroll 1
      for (int i = 0; i < 3; ++i) {
        const int jR = wid*3 + i;
        const int jZ = 12 + wid*3 + i;
        const int jI = 24 + wid*3 + i;
        const int jH = 36 + wid*3 + i;
        f32x4 aR0 = (f32x4)0.f, aR1 = (f32x4)0.f;
        f32x4 aZ0 = (f32x4)0.f, aZ1 = (f32x4)0.f;
        f32x4 aI0 = (f32x4)0.f, aI1 = (f32x4)0.f;
        f32x4 aH0 = (f32x4)0.f, aH1 = (f32x4)0.f;
        #pragma unroll
        for (int kt = 0; kt < NKT; ++kt) {
          f16x8 ah0 = *(const f16x8*)(ahb + kt*64);
          f16x8 ah1 = *(const f16x8*)(ahb + 16*(GRUPU*4) + kt*64);
          f16x8 bR = *(const f16x8*)(Bh + (((size_t)(jR*NKT + kt)) << 9) + lane*8);
          f16x8 bZ = *(const f16x8*)(Bh + (((size_t)(jZ*NKT + kt)) << 9) + lane*8);
          f16x8 bH = *(const f16x8*)(Bh + (((size_t)(jH*NKT + kt)) << 9) + lane*8);
          aR0 = __builtin_amdgcn_mfma_f32_16x16x32_f16(ah0, bR, aR0, 0, 0, 0);
          aR1 = __builtin_amdgcn_mfma_f32_16x16x32_f16(ah1, bR, aR1, 0, 0, 0);
          aZ0 = __builtin_amdgcn_mfma_f32_16x16x32_f16(ah0, bZ, aZ0, 0, 0, 0);
          aZ1 = __builtin_amdgcn_mfma_f32_16x16x32_f16(ah1, bZ, aZ1, 0, 0, 0);
          aH0 = __builtin_amdgcn_mfma_f32_16x16x32_f16(ah0, bH, aH0, 0, 0, 0);
          aH1 = __builtin_amdgcn_mfma_f32_16x16x32_f16(ah1, bH, aH1, 0, 0, 0);
          if (kt == 0) {
            f16x8 bI = *(const f16x8*)(Bh + (((size_t)(jI*NKT)) << 9) + lane*8);
            aI0 = __builtin_amdgcn_mfma_f32_16x16x32_f16(ah0, bI, aI0, 0, 0, 0);
            aI1 = __builtin_amdgcn_mfma_f32_16x16x32_f16(ah1, bI, aI1, 0, 0, 0);
          }
        }
        const int d = (wid*3 + i)*16 + col;
        const float bR_ = bias768[d],       bZ_ = bias768[192 + d];
        const float bI_ = bias768[384 + d], bH_ = bias768[576 + d];
        #pragma unroll
        for (int q = 0; q < 4; ++q) {
          const int g0 = quad*4 + q;
          float r_ = fsig(aR0[q] + bR_);
          float z_ = fsig(aZ0[q] + bZ_);
          float n_ = ftanh(aI0[q] + bI_ + r_*(aH0[q] + bH_));
          float hold = sh_h[g0][d];
          sh_h[g0][d] = (1.f - z_)*n_ + z_*hold;
        }
        #pragma unroll
        for (int q = 0; q < 4; ++q) {
          const int g1 = 16 + quad*4 + q;
          if (g1 < ROWS) {
            float r_ = fsig(aR1[q] + bR_);
            float z_ = fsig(aZ1[q] + bZ_);
            float n_ = ftanh(aI1[q] + bI_ + r_*(aH1[q] + bH_));
            float hold = sh_h[g1][d];
            sh_h[g1][d] = (1.f - z_)*n_ + z_*hold;
          }
        }
      }
    }
    __syncthreads();
  }

  // ---- conv: h-load once per element, 6 FMAs inside ----
  {
    float acco[OO];
    #pragma unroll
    for (int o = 0; o < OO; ++o) acco[o] = 0.f;
    for (int u = tid; u < DD*TT*NN; u += 256) {
      int r = u % ROWS, c = u / ROWS;
      float hv = sh_h[r][c];
      #pragma unroll
      for (int o = 0; o < OO; ++o)
        acco[o] += conv1_w[o*(DD*TT*NN) + u] * hv;
    }
    #pragma unroll
    for (int o = 0; o < OO; ++o) {
      float v = acco[o];
      v += __shfl_xor(v, 1);  v += __shfl_xor(v, 2);  v += __shfl_xor(v, 4);
      v += __shfl_xor(v, 8);  v += __shfl_xor(v, 16); v += __shfl_xor(v, 32);
      acco[o] = v;
    }
    if (lane == 0) {
      #pragma unroll
      for (int o = 0; o < OO; ++o) red[wid][o] = acco[o];
    }
    __syncthreads();
    if (tid == 0) {
      float y[OO];
      #pragma unroll
      for (int o = 0; o < OO; ++o) {
        float s = conv1_b[o] + red[0][o] + red[1][o] + red[2][o] + red[3][o];
        y[o] = fmaxf(s, 0.f);
      }
      #pragma unroll
      for (int q = 0; q < OO; ++q) {
        float s = conv2_b[q];
        #pragma unroll
        for (int o = 0; o < OO; ++o) s += conv2_w[q*OO + o] * y[o];
        out[b*OO + q] = s;
      }
    }
  }
}

// ---------------------------------------------------------------- launch
extern "C" void kernel_launch(void* const* d_in, const int* in_sizes, int n_in,
                              void* d_out, int out_size, void* d_ws, size_t ws_size,
                              hipStream_t stream) {
  const float* node_resnet = (const float*)d_in[0];
  const float* pos      = (const float*)d_in[1];
  const int*   attmat   = (const int*)  d_in[2];
  const float* link_w1  = (const float*)d_in[3];
  const float* link_b1  = (const float*)d_in[4];
  const float* link_w2  = (const float*)d_in[5];
  const float* link_b2  = (const float*)d_in[6];
  const float* msg_Wh   = (const float*)d_in[7];
  const float* msg_We   = (const float*)d_in[8];
  const float* msg_b    = (const float*)d_in[9];
  const float* gru_Wih  = (const float*)d_in[10];
  const float* gru_Whh  = (const float*)d_in[11];
  const float* gru_bih  = (const float*)d_in[12];
  const float* gru_bhh  = (const float*)d_in[13];
  const float* conv1_w  = (const float*)d_in[14];
  const float* conv1_b  = (const float*)d_in[15];
  const float* conv2_w  = (const float*)d_in[16];
  const float* conv2_b  = (const float*)d_in[17];
  float* out = (float*)d_out;

  // ws layout: bias768 | Bh(fp16) | BLh(fp16)   (~0.4 MB)
  float* bias = (float*)d_ws;
  unsigned short* Bh  = (unsigned short*)(bias + GOUT);
  unsigned short* BLh = Bh + (size_t)NJT*NKT*512;

  k_pack<<<(NJT*NKT*512 + 255)/256, 256, 0, stream>>>(gru_Wih, gru_Whh,
      gru_bih, gru_bhh, Bh, bias);
  k_pack_link<<<(32*512 + 255)/256, 256, 0, stream>>>(link_w1, link_b1, BLh);
  k_fused<<<NB, 256, 0, stream>>>(node_resnet, pos, attmat,
      BLh, link_w2, link_b2,
      msg_Wh, msg_We, msg_b,
      Bh, bias,
      conv1_w, conv1_b, conv2_w, conv2_b, out);
}

// Round 13
// 166.090 us; speedup vs baseline: 1.3071x; 1.3071x over previous
//
#include <hip/hip_runtime.h>
#include <math.h>

// Sizes (fixed by the reference)
#define NB 1024
#define TT 5
#define NN 6
#define DD 192
#define EE 12
#define MM 12
#define LL 512
#define OO 6
#define GOUT 768              // GRU GEMM N: [r|z|inn|hn]
#define KPAD 224              // GRU K: 12 + 192 + 20 pad
#define NKT (KPAD/32)         // 7 k-tiles
#define NJT (GOUT/16)         // 48 n-tiles

#define ROWS 30               // (t,n) rows per batch
#define HP 196                // sh_h pitch (floats)
#define LNKPU 20              // linkA pitch (uints)
#define GRUPU 116             // gruA pitch (uints) = 464 B

typedef __attribute__((ext_vector_type(8))) _Float16 f16x8;
typedef __attribute__((ext_vector_type(4))) float f32x4;

__device__ __forceinline__ float dot4(float4 a, float4 b) {
  return a.x*b.x + a.y*b.y + a.z*b.z + a.w*b.w;
}
__device__ __forceinline__ unsigned short f2h(float f) {
  _Float16 h = (_Float16)f;
  unsigned short s; __builtin_memcpy(&s, &h, 2); return s;
}
// pack two f32 -> fp16x2 in ONE instruction (v_cvt_pkrtz_f16_f32)
__device__ __forceinline__ unsigned int pkrtz(float a, float b) {
  auto v = __builtin_amdgcn_cvt_pkrtz(a, b);
  return __builtin_bit_cast(unsigned int, v);
}
// fast sigmoid / tanh (v_exp + v_rcp)
__device__ __forceinline__ float fsig(float x) {
  float e = __expf(-x);
  return __builtin_amdgcn_rcpf(1.f + e);
}
// tanh(x) = 2/(1+exp(-2x)) - 1  (sign-verified: x->+inf => +1)
__device__ __forceinline__ float ftanh(float x) {
  float e = __expf(-2.f * x);
  return 2.f * __builtin_amdgcn_rcpf(1.f + e) - 1.f;
}

// ---------------------------------------------------------------- k_pack (GRU W, fp16)
__global__ void k_pack(const float* __restrict__ Wih, const float* __restrict__ Whh,
                       const float* __restrict__ bih, const float* __restrict__ bhh,
                       unsigned short* __restrict__ Bh, float* __restrict__ bias768)
{
  int idx = blockIdx.x * 256 + threadIdx.x;
  if (idx < GOUT) {
    int c = idx; float b;
    if (c < 384)      b = bih[c] + bhh[c];
    else if (c < 576) b = bih[c];
    else              b = bhh[c - 192];
    bias768[c] = b;
  }
  if (idx >= NJT*NKT*512) return;
  int e = idx & 7, l = (idx >> 3) & 63;
  int rem = idx >> 9, kt = rem % NKT, j = rem / NKT;
  int k = kt*32 + ((l >> 4) << 3) + e;
  int c = j*16 + (l & 15);
  float v = 0.f;
  if (k < 204) {
    if (c < 384)      v = (k < 12) ? Wih[c*MM + k] : Whh[(size_t)c*DD + (k-12)];
    else if (c < 576) v = (k < 12) ? Wih[c*MM + k] : 0.f;
    else              v = (k < 12) ? 0.f : Whh[(size_t)(c-192)*DD + (k-12)];
  }
  Bh[idx] = f2h(v);
}

// ---------------------------------------------------------------- k_pack_link (fp16)
// W1^T with b1 folded at k==12 (A supplies 1.0 there).
__global__ void k_pack_link(const float* __restrict__ w1, const float* __restrict__ b1,
                            unsigned short* __restrict__ BLh)
{
  int idx = blockIdx.x * 256 + threadIdx.x;
  if (idx >= 32*512) return;
  int e = idx & 7, l = (idx >> 3) & 63, nt = idx >> 9;
  int k = ((l >> 4) << 3) + e;
  int c = nt*16 + (l & 15);
  float v = 0.f;
  if (k < 12)       v = w1[c*EE + k];
  else if (k == 12) v = b1[c];
  BLh[idx] = f2h(v);
}

// ---------------------------------------------------------------- k_fused
// Round-8 structure EXACTLY (known no-spill: (256,2), fp32 sh_e/sh_m, separate
// msum phase) + only arithmetic-class changes: fast trig (E), conv
// interchange (F), w2-LDS + b1-fold (D), pkrtz packer. Bisect experiment:
// spill suspects A=(256,3), B=fp16 e/m, C=inline msum are EXCLUDED.
__global__ __launch_bounds__(256, 2)
void k_fused(const float* __restrict__ nr, const float* __restrict__ pos,
             const int* __restrict__ attmat,
             const unsigned short* __restrict__ BLh,
             const float* __restrict__ lw2, const float* __restrict__ lb2,
             const float* __restrict__ msg_Wh, const float* __restrict__ msg_We,
             const float* __restrict__ msg_b,
             const unsigned short* __restrict__ Bh, const float* __restrict__ bias768,
             const float* __restrict__ conv1_w, const float* __restrict__ conv1_b,
             const float* __restrict__ conv2_w, const float* __restrict__ conv2_b,
             float* __restrict__ out)
{
  __shared__ __align__(16) float sh_h[ROWS][HP];        // 23520 B fp32 node state
  __shared__ __align__(16) float sh_e[180][EE];         // 8640 B fp32 edge feats
  __shared__ __align__(16) float sh_m[180][MM];         // 8640 B fp32 messages
  __shared__ __align__(16) float sh_mh[ROWS][MM];       // 1440 B
  __shared__ __align__(16) float sh_msum[ROWS][MM];     // 1440 B
  __shared__ float sh_adj[192];                         // 768 B
  __shared__ float sh_w2[LL];                           // 2048 B
  __shared__ __align__(16) unsigned int shA[192*LNKPU]; // 15360 B (linkA|gruA)
  __shared__ float red[4][OO];

  const int tid = threadIdx.x;
  const int b = blockIdx.x;
  const int lane = tid & 63, wid = tid >> 6;
  const int col = lane & 15, quad = lane >> 4;

  // ---- Phase 0: h, edge features, w2 ----
  for (int i = tid; i < TT*DD*NN; i += 256) {
    int t = i / (DD*NN), rem = i % (DD*NN);
    int d = rem / NN, n = rem % NN;
    sh_h[t*NN + n][d] = nr[(size_t)b*TT*DD*NN + i];     // coalesced
  }
  for (int idx = tid; idx < 180*EE; idx += 256) {
    int e = idx / EE, c = idx % EE;
    int t = e / 36, ij = e % 36;
    int i_ = ij / NN, j_ = ij % NN;
    bool msk = (attmat[(b*TT + t)*36 + ij] == 1) && (i_ != j_);
    int srcn = (c < 6) ? i_ : j_;
    int cc   = (c < 6) ? c  : c - 6;
    sh_e[e][c] = msk ? pos[((b*TT + t)*NN + srcn)*6 + cc] : 0.f;
  }
  for (int i = tid; i < LL; i += 256) sh_w2[i] = lw2[i];
  __syncthreads();

  for (int L = 0; L < 2; ++L) {
    // ---- link A staging: fp32 -> fp16; 1.0 at k==12 (b1 fold) ----
    for (int idx = tid; idx < 192*16; idx += 256) {
      int r = idx >> 4, p = idx & 15;
      unsigned int v = 0;
      if (r < 180) {
        if (p < 6) {
          const float* src = (L == 0) ? &sh_e[r][0] : &sh_m[r][0];
          v = pkrtz(src[2*p], src[2*p+1]);
        } else if (p == 6) {
          v = 0x00003C00u;   // (1.0h, 0)
        }
      }
      shA[r*LNKPU + p] = v;
    }
    __syncthreads();

    // ---- link MFMA: wave owns m-tiles {wid*3..+2}; fused relu->w2->sigmoid ----
    {
      f16x8 am[3];
      #pragma unroll
      for (int mtl = 0; mtl < 3; ++mtl)
        am[mtl] = *(const f16x8*)((const char*)shA
                    + ((wid*3 + mtl)*16 + col)*(LNKPU*4) + quad*16);
      float s[3][4];
      #pragma unroll
      for (int mtl = 0; mtl < 3; ++mtl)
        #pragma unroll
        for (int q = 0; q < 4; ++q) s[mtl][q] = 0.f;
      for (int nt = 0; nt < 32; ++nt) {
        f16x8 bh = *(const f16x8*)(BLh + nt*512 + lane*8);
        float w2v = sh_w2[nt*16 + col];
        #pragma unroll
        for (int mtl = 0; mtl < 3; ++mtl) {
          f32x4 acc = (f32x4)0.f;
          acc = __builtin_amdgcn_mfma_f32_16x16x32_f16(am[mtl], bh, acc, 0, 0, 0);
          #pragma unroll
          for (int q = 0; q < 4; ++q)
            s[mtl][q] += w2v * fmaxf(acc[q], 0.f);   // b1 folded into acc
        }
      }
      #pragma unroll
      for (int mtl = 0; mtl < 3; ++mtl)
        #pragma unroll
        for (int q = 0; q < 4; ++q) {
          float v = s[mtl][q];
          v += __shfl_xor(v, 1); v += __shfl_xor(v, 2);
          v += __shfl_xor(v, 4); v += __shfl_xor(v, 8);
          s[mtl][q] = v;
        }
      if (col == 0) {
        float b2 = lb2[0];
        #pragma unroll
        for (int mtl = 0; mtl < 3; ++mtl)
          #pragma unroll
          for (int q = 0; q < 4; ++q)
            sh_adj[wid*48 + mtl*16 + quad*4 + q] = fsig(s[mtl][q] + b2);
      }
    }
    __syncthreads();

    // ---- mh[r][o] = msg_b[o] + Wh[o,:] . h[r,:] ----
    for (int idx = tid; idx < ROWS*MM; idx += 256) {
      int r = idx / MM, o = idx % MM;
      const float4* wrow = (const float4*)(msg_Wh + (size_t)o*DD);
      const float4* hrow = (const float4*)&sh_h[r][0];
      float acc = msg_b[o];
      #pragma unroll 8
      for (int d4 = 0; d4 < DD/4; ++d4) acc += dot4(wrow[d4], hrow[d4]);
      sh_mh[r][o] = acc;
    }
    __syncthreads();

    // ---- m = adj * relu(mh_j + We.e) ----
    for (int idx = tid; idx < 180*MM; idx += 256) {
      int e = idx / MM, o = idx % MM;
      int t = e / 36, j_ = e % NN;
      const float4* we = (const float4*)(msg_We + o*EE);
      const float4* ev = (const float4*)&sh_e[e][0];
      float me = dot4(we[0],ev[0]) + dot4(we[1],ev[1]) + dot4(we[2],ev[2]);
      sh_m[e][o] = sh_adj[e] * fmaxf(sh_mh[t*NN + j_][o] + me, 0.f);
    }
    __syncthreads();

    // ---- msum[r=t*6+i][o] = sum_j m[t*36+i*6+j][o] ----
    for (int idx = tid; idx < ROWS*MM; idx += 256) {
      int r = idx / MM, o = idx % MM;
      int t = r / NN, i_ = r % NN;
      float s = 0.f;
      #pragma unroll
      for (int j = 0; j < NN; ++j) s += sh_m[t*36 + i_*NN + j][o];
      sh_msum[r][o] = s;
    }
    __syncthreads();

    // ---- GRU A staging: 32 rows x 224 k, fp16 (aliases linkA) ----
    for (int idx = tid; idx < 32*(KPAD/2); idx += 256) {
      int r = idx / (KPAD/2), kp = idx % (KPAD/2);
      int k0 = 2*kp, k1 = k0 + 1;
      float a0 = 0.f, a1 = 0.f;
      if (r < ROWS) {
        a0 = (k0 < 12) ? sh_msum[r][k0] : (k0 < 204 ? sh_h[r][k0-12] : 0.f);
        a1 = (k1 < 12) ? sh_msum[r][k1] : (k1 < 204 ? sh_h[r][k1-12] : 0.f);
      }
      shA[r*GRUPU + kp] = pkrtz(a0, a1);
    }
    __syncthreads();

    // ---- GRU MFMA, one d-tile at a time (no spill) ----
    {
      const char* ahb = (const char*)shA + col*(GRUPU*4) + quad*16;
      #pragma unroll 1
      for (int i = 0; i < 3; ++i) {
        const int jR = wid*3 + i;
        const int jZ = 12 + wid*3 + i;
        const int jI = 24 + wid*3 + i;
        const int jH = 36 + wid*3 + i;
        f32x4 aR0 = (f32x4)0.f, aR1 = (f32x4)0.f;
        f32x4 aZ0 = (f32x4)0.f, aZ1 = (f32x4)0.f;
        f32x4 aI0 = (f32x4)0.f, aI1 = (f32x4)0.f;
        f32x4 aH0 = (f32x4)0.f, aH1 = (f32x4)0.f;
        #pragma unroll
        for (int kt = 0; kt < NKT; ++kt) {
          f16x8 ah0 = *(const f16x8*)(ahb + kt*64);
          f16x8 ah1 = *(const f16x8*)(ahb + 16*(GRUPU*4) + kt*64);
          f16x8 bR = *(const f16x8*)(Bh + (((size_t)(jR*NKT + kt)) << 9) + lane*8);
          f16x8 bZ = *(const f16x8*)(Bh + (((size_t)(jZ*NKT + kt)) << 9) + lane*8);
          f16x8 bH = *(const f16x8*)(Bh + (((size_t)(jH*NKT + kt)) << 9) + lane*8);
          aR0 = __builtin_amdgcn_mfma_f32_16x16x32_f16(ah0, bR, aR0, 0, 0, 0);
          aR1 = __builtin_amdgcn_mfma_f32_16x16x32_f16(ah1, bR, aR1, 0, 0, 0);
          aZ0 = __builtin_amdgcn_mfma_f32_16x16x32_f16(ah0, bZ, aZ0, 0, 0, 0);
          aZ1 = __builtin_amdgcn_mfma_f32_16x16x32_f16(ah1, bZ, aZ1, 0, 0, 0);
          aH0 = __builtin_amdgcn_mfma_f32_16x16x32_f16(ah0, bH, aH0, 0, 0, 0);
          aH1 = __builtin_amdgcn_mfma_f32_16x16x32_f16(ah1, bH, aH1, 0, 0, 0);
          if (kt == 0) {
            f16x8 bI = *(const f16x8*)(Bh + (((size_t)(jI*NKT)) << 9) + lane*8);
            aI0 = __builtin_amdgcn_mfma_f32_16x16x32_f16(ah0, bI, aI0, 0, 0, 0);
            aI1 = __builtin_amdgcn_mfma_f32_16x16x32_f16(ah1, bI, aI1, 0, 0, 0);
          }
        }
        const int d = (wid*3 + i)*16 + col;
        const float bR_ = bias768[d],       bZ_ = bias768[192 + d];
        const float bI_ = bias768[384 + d], bH_ = bias768[576 + d];
        #pragma unroll
        for (int q = 0; q < 4; ++q) {
          const int g0 = quad*4 + q;        // rows 0..15: always < ROWS
          float r_ = fsig(aR0[q] + bR_);
          float z_ = fsig(aZ0[q] + bZ_);
          float n_ = ftanh(aI0[q] + bI_ + r_*(aH0[q] + bH_));
          float hold = sh_h[g0][d];
          sh_h[g0][d] = (1.f - z_)*n_ + z_*hold;
        }
        #pragma unroll
        for (int q = 0; q < 4; ++q) {
          const int g1 = 16 + quad*4 + q;   // rows 16..31: guard < 30
          if (g1 < ROWS) {
            float r_ = fsig(aR1[q] + bR_);
            float z_ = fsig(aZ1[q] + bZ_);
            float n_ = ftanh(aI1[q] + bI_ + r_*(aH1[q] + bH_));
            float hold = sh_h[g1][d];
            sh_h[g1][d] = (1.f - z_)*n_ + z_*hold;
          }
        }
      }
    }
    __syncthreads();
  }

  // ---- conv: h-load + index math once per element, 6 FMAs inside ----
  {
    float acco[OO];
    #pragma unroll
    for (int o = 0; o < OO; ++o) acco[o] = 0.f;
    for (int u = tid; u < DD*TT*NN; u += 256) {
      int r = u % ROWS, c = u / ROWS;
      float hv = sh_h[r][c];
      #pragma unroll
      for (int o = 0; o < OO; ++o)
        acco[o] += conv1_w[o*(DD*TT*NN) + u] * hv;
    }
    #pragma unroll
    for (int o = 0; o < OO; ++o) {
      float v = acco[o];
      v += __shfl_xor(v, 1);  v += __shfl_xor(v, 2);  v += __shfl_xor(v, 4);
      v += __shfl_xor(v, 8);  v += __shfl_xor(v, 16); v += __shfl_xor(v, 32);
      acco[o] = v;
    }
    if (lane == 0) {
      #pragma unroll
      for (int o = 0; o < OO; ++o) red[wid][o] = acco[o];
    }
    __syncthreads();
    if (tid == 0) {
      float y[OO];
      #pragma unroll
      for (int o = 0; o < OO; ++o) {
        float s = conv1_b[o] + red[0][o] + red[1][o] + red[2][o] + red[3][o];
        y[o] = fmaxf(s, 0.f);
      }
      #pragma unroll
      for (int q = 0; q < OO; ++q) {
        float s = conv2_b[q];
        #pragma unroll
        for (int o = 0; o < OO; ++o) s += conv2_w[q*OO + o] * y[o];
        out[b*OO + q] = s;
      }
    }
  }
}

// ---------------------------------------------------------------- launch
extern "C" void kernel_launch(void* const* d_in, const int* in_sizes, int n_in,
                              void* d_out, int out_size, void* d_ws, size_t ws_size,
                              hipStream_t stream) {
  const float* node_resnet = (const float*)d_in[0];
  const float* pos      = (const float*)d_in[1];
  const int*   attmat   = (const int*)  d_in[2];
  const float* link_w1  = (const float*)d_in[3];
  const float* link_b1  = (const float*)d_in[4];
  const float* link_w2  = (const float*)d_in[5];
  const float* link_b2  = (const float*)d_in[6];
  const float* msg_Wh   = (const float*)d_in[7];
  const float* msg_We   = (const float*)d_in[8];
  const float* msg_b    = (const float*)d_in[9];
  const float* gru_Wih  = (const float*)d_in[10];
  const float* gru_Whh  = (const float*)d_in[11];
  const float* gru_bih  = (const float*)d_in[12];
  const float* gru_bhh  = (const float*)d_in[13];
  const float* conv1_w  = (const float*)d_in[14];
  const float* conv1_b  = (const float*)d_in[15];
  const float* conv2_w  = (const float*)d_in[16];
  const float* conv2_b  = (const float*)d_in[17];
  float* out = (float*)d_out;

  // ws layout: bias768 | Bh(fp16) | BLh(fp16)   (~0.4 MB)
  float* bias = (float*)d_ws;
  unsigned short* Bh  = (unsigned short*)(bias + GOUT);
  unsigned short* BLh = Bh + (size_t)NJT*NKT*512;

  k_pack<<<(NJT*NKT*512 + 255)/256, 256, 0, stream>>>(gru_Wih, gru_Whh,
      gru_bih, gru_bhh, Bh, bias);
  k_pack_link<<<(32*512 + 255)/256, 256, 0, stream>>>(link_w1, link_b1, BLh);
  k_fused<<<NB, 256, 0, stream>>>(node_resnet, pos, attmat,
      BLh, link_w2, link_b2,
      msg_Wh, msg_We, msg_b,
      Bh, bias,
      conv1_w, conv1_b, conv2_w, conv2_b, out);
}

// Round 14
// 156.105 us; speedup vs baseline: 1.3907x; 1.0640x over previous
//
#include <hip/hip_runtime.h>
#include <math.h>

// Sizes (fixed by the reference)
#define NB 1024
#define TT 5
#define NN 6
#define DD 192
#define EE 12
#define MM 12
#define LL 512
#define OO 6
#define GOUT 768              // GRU GEMM N: [r|z|inn|hn]
#define KPAD 224              // GRU K: 12 + 192 + 20 pad
#define NKT (KPAD/32)         // 7 k-tiles
#define NJT (GOUT/16)         // 48 n-tiles

#define ROWS 30               // (t,n) rows per batch
#define HP 196                // sh_h pitch (floats)
#define LNKPU 20              // linkA pitch (uints)
#define GRUPU 116             // gruA pitch (uints) = 464 B

typedef __attribute__((ext_vector_type(8))) _Float16 f16x8;
typedef __attribute__((ext_vector_type(2))) _Float16 h2;
typedef __attribute__((ext_vector_type(4))) float f32x4;

__device__ __forceinline__ float dot4(float4 a, float4 b) {
  return a.x*b.x + a.y*b.y + a.z*b.z + a.w*b.w;
}
__device__ __forceinline__ unsigned short f2h(float f) {
  _Float16 h = (_Float16)f;
  unsigned short s; __builtin_memcpy(&s, &h, 2); return s;
}
// pack two f32 -> fp16x2 in ONE instruction (v_cvt_pkrtz_f16_f32)
__device__ __forceinline__ unsigned int pkrtz(float a, float b) {
  auto v = __builtin_amdgcn_cvt_pkrtz(a, b);
  return __builtin_bit_cast(unsigned int, v);
}
// fast sigmoid / tanh (v_exp + v_rcp)
__device__ __forceinline__ float fsig(float x) {
  float e = __expf(-x);
  return __builtin_amdgcn_rcpf(1.f + e);
}
// tanh(x) = 2/(1+exp(-2x)) - 1  (sign-verified)
__device__ __forceinline__ float ftanh(float x) {
  float e = __expf(-2.f * x);
  return 2.f * __builtin_amdgcn_rcpf(1.f + e) - 1.f;
}

// ---------------------------------------------------------------- k_pack (GRU W, fp16)
__global__ void k_pack(const float* __restrict__ Wih, const float* __restrict__ Whh,
                       const float* __restrict__ bih, const float* __restrict__ bhh,
                       unsigned short* __restrict__ Bh, float* __restrict__ bias768)
{
  int idx = blockIdx.x * 256 + threadIdx.x;
  if (idx < GOUT) {
    int c = idx; float b;
    if (c < 384)      b = bih[c] + bhh[c];
    else if (c < 576) b = bih[c];
    else              b = bhh[c - 192];
    bias768[c] = b;
  }
  if (idx >= NJT*NKT*512) return;
  int e = idx & 7, l = (idx >> 3) & 63;
  int rem = idx >> 9, kt = rem % NKT, j = rem / NKT;
  int k = kt*32 + ((l >> 4) << 3) + e;
  int c = j*16 + (l & 15);
  float v = 0.f;
  if (k < 204) {
    if (c < 384)      v = (k < 12) ? Wih[c*MM + k] : Whh[(size_t)c*DD + (k-12)];
    else if (c < 576) v = (k < 12) ? Wih[c*MM + k] : 0.f;
    else              v = (k < 12) ? 0.f : Whh[(size_t)(c-192)*DD + (k-12)];
  }
  Bh[idx] = f2h(v);
}

// ---------------------------------------------------------------- k_pack_link (fp16)
// W1^T with b1 folded at k==12 (A supplies 1.0 there).
__global__ void k_pack_link(const float* __restrict__ w1, const float* __restrict__ b1,
                            unsigned short* __restrict__ BLh)
{
  int idx = blockIdx.x * 256 + threadIdx.x;
  if (idx >= 32*512) return;
  int e = idx & 7, l = (idx >> 3) & 63, nt = idx >> 9;
  int k = ((l >> 4) << 3) + e;
  int c = nt*16 + (l & 15);
  float v = 0.f;
  if (k < 12)       v = w1[c*EE + k];
  else if (k == 12) v = b1[c];
  BLh[idx] = f2h(v);
}

// ---------------------------------------------------------------- k_fused
// One WG per batch. LDS 52.2KB -> 3 WG/CU (LDS-wise). __launch_bounds__(256,2):
// bisect (r8..r13) proved (256,3) caps the allocator at ~85 VGPR while the
// kernel needs ~128 -> 106MB+106MB scratch spill traffic. (256,2) lets VGPR=128
// (4 waves/SIMD reg-wise); occupancy is then LDS-limited at 3 WG/CU.
__global__ __launch_bounds__(256, 2)
void k_fused(const float* __restrict__ nr, const float* __restrict__ pos,
             const int* __restrict__ attmat,
             const unsigned short* __restrict__ BLh,
             const float* __restrict__ lw2, const float* __restrict__ lb2,
             const float* __restrict__ msg_Wh, const float* __restrict__ msg_We,
             const float* __restrict__ msg_b,
             const unsigned short* __restrict__ Bh, const float* __restrict__ bias768,
             const float* __restrict__ conv1_w, const float* __restrict__ conv1_b,
             const float* __restrict__ conv2_w, const float* __restrict__ conv2_b,
             float* __restrict__ out)
{
  __shared__ __align__(16) float sh_h[ROWS][HP];          // 23520 B fp32 state
  __shared__ __align__(16) unsigned int sh_e[180][6];     // 4320 B fp16x2 edge feats
  __shared__ __align__(16) unsigned int sh_m[180][6];     // 4320 B fp16x2 messages
  __shared__ __align__(16) float sh_mh[ROWS][MM];         // 1440 B
  __shared__ float sh_adj[192];                           // 768 B
  __shared__ float sh_w2[LL];                             // 2048 B
  __shared__ __align__(16) unsigned int sh_we[MM][6];     // 288 B fp16x2 msg_We
  __shared__ __align__(16) unsigned int shA[192*LNKPU];   // 15360 B (linkA|gruA)
  __shared__ float red[4][OO];

  const int tid = threadIdx.x;
  const int b = blockIdx.x;
  const int lane = tid & 63, wid = tid >> 6;
  const int col = lane & 15, quad = lane >> 4;

  // ---- Phase 0: h, edge feats (fp16), We (fp16), w2 ----
  for (int i = tid; i < TT*DD*NN; i += 256) {
    int t = i / (DD*NN), rem = i % (DD*NN);
    int d = rem / NN, n = rem % NN;
    sh_h[t*NN + n][d] = nr[(size_t)b*TT*DD*NN + i];       // coalesced
  }
  for (int idx = tid; idx < 180*6; idx += 256) {
    int e = idx / 6, p = idx % 6;
    int t = e / 36, ij = e % 36;
    int i_ = ij / NN, j_ = ij % NN;
    bool msk = (attmat[(b*TT + t)*36 + ij] == 1) && (i_ != j_);
    int srcn = (p < 3) ? i_ : j_;
    int c0   = (p < 3) ? 2*p : 2*p - 6;
    const float* pb = pos + (((size_t)(b*TT + t))*NN + srcn)*6;
    float a0 = msk ? pb[c0] : 0.f, a1 = msk ? pb[c0+1] : 0.f;
    sh_e[e][p] = pkrtz(a0, a1);
  }
  for (int idx = tid; idx < MM*6; idx += 256) {
    int o = idx / 6, p = idx % 6;
    sh_we[o][p] = pkrtz(msg_We[o*EE + 2*p], msg_We[o*EE + 2*p + 1]);
  }
  for (int i = tid; i < LL; i += 256) sh_w2[i] = lw2[i];
  __syncthreads();

  for (int L = 0; L < 2; ++L) {
    // ---- link A staging: pure fp16 copy (+1.0 at k=12 for b1 fold) ----
    for (int idx = tid; idx < 192*16; idx += 256) {
      int r = idx >> 4, p = idx & 15;
      unsigned int v = 0;
      if (r < 180) {
        if (p < 6)       v = (L == 0) ? sh_e[r][p] : sh_m[r][p];
        else if (p == 6) v = 0x00003C00u;   // (1.0h, 0)
      }
      shA[r*LNKPU + p] = v;
    }
    __syncthreads();

    // ---- link MFMA: wave owns m-tiles {wid*3..+2}; fused relu->w2->sigmoid ----
    {
      f16x8 am[3];
      #pragma unroll
      for (int mtl = 0; mtl < 3; ++mtl)
        am[mtl] = *(const f16x8*)((const char*)shA
                    + ((wid*3 + mtl)*16 + col)*(LNKPU*4) + quad*16);
      float s[3][4];
      #pragma unroll
      for (int mtl = 0; mtl < 3; ++mtl)
        #pragma unroll
        for (int q = 0; q < 4; ++q) s[mtl][q] = 0.f;
      for (int nt = 0; nt < 32; ++nt) {
        f16x8 bh = *(const f16x8*)(BLh + nt*512 + lane*8);
        float w2v = sh_w2[nt*16 + col];
        #pragma unroll
        for (int mtl = 0; mtl < 3; ++mtl) {
          f32x4 acc = (f32x4)0.f;
          acc = __builtin_amdgcn_mfma_f32_16x16x32_f16(am[mtl], bh, acc, 0, 0, 0);
          #pragma unroll
          for (int q = 0; q < 4; ++q)
            s[mtl][q] += w2v * fmaxf(acc[q], 0.f);   // b1 folded into acc
        }
      }
      #pragma unroll
      for (int mtl = 0; mtl < 3; ++mtl)
        #pragma unroll
        for (int q = 0; q < 4; ++q) {
          float v = s[mtl][q];
          v += __shfl_xor(v, 1); v += __shfl_xor(v, 2);
          v += __shfl_xor(v, 4); v += __shfl_xor(v, 8);
          s[mtl][q] = v;
        }
      if (col == 0) {
        float b2 = lb2[0];
        #pragma unroll
        for (int mtl = 0; mtl < 3; ++mtl)
          #pragma unroll
          for (int q = 0; q < 4; ++q)
            sh_adj[wid*48 + mtl*16 + quad*4 + q] = fsig(s[mtl][q] + b2);
      }
    }
    __syncthreads();

    // ---- mh[r][o] = msg_b[o] + Wh[o,:] . h[r,:] ----
    for (int idx = tid; idx < ROWS*MM; idx += 256) {
      int r = idx / MM, o = idx % MM;
      const float4* wrow = (const float4*)(msg_Wh + (size_t)o*DD);
      const float4* hrow = (const float4*)&sh_h[r][0];
      float acc = msg_b[o];
      #pragma unroll 8
      for (int d4 = 0; d4 < DD/4; ++d4) acc += dot4(wrow[d4], hrow[d4]);
      sh_mh[r][o] = acc;
    }
    __syncthreads();

    // ---- m = adj * relu(mh_j + We.e)  (half2 me, packed store) ----
    for (int idx = tid; idx < 180*6; idx += 256) {
      int e = idx / 6, op = idx % 6;
      int t = e / 36, j_ = e % 6;
      h2 a2 = {(_Float16)0.f, (_Float16)0.f};
      h2 b2 = {(_Float16)0.f, (_Float16)0.f};
      #pragma unroll
      for (int p = 0; p < 6; ++p) {
        h2 ev = __builtin_bit_cast(h2, sh_e[e][p]);
        a2 += __builtin_bit_cast(h2, sh_we[2*op][p]) * ev;
        b2 += __builtin_bit_cast(h2, sh_we[2*op+1][p]) * ev;
      }
      float me0 = (float)a2[0] + (float)a2[1];
      float me1 = (float)b2[0] + (float)b2[1];
      float mh0 = sh_mh[t*NN + j_][2*op];
      float mh1 = sh_mh[t*NN + j_][2*op+1];
      float adj = sh_adj[e];
      sh_m[e][op] = pkrtz(adj * fmaxf(mh0 + me0, 0.f),
                          adj * fmaxf(mh1 + me1, 0.f));
    }
    __syncthreads();

    // ---- GRU A staging (x-sums inline; h fp32->fp16) ----
    for (int idx = tid; idx < 32*(KPAD/2); idx += 256) {
      int r = idx / (KPAD/2), kp = idx % (KPAD/2);
      unsigned int v = 0;
      if (r < ROWS) {
        if (kp < 6) {            // k0,k1 < 12: msum over 6 source nodes
          int t = r / NN, i_ = r % NN;
          const unsigned int* mrow = &sh_m[t*36 + i_*NN][kp];
          float a0 = 0.f, a1 = 0.f;
          #pragma unroll
          for (int j = 0; j < 6; ++j) {
            h2 mv = __builtin_bit_cast(h2, mrow[j*6]);
            a0 += (float)mv[0]; a1 += (float)mv[1];
          }
          v = pkrtz(a0, a1);
        } else if (kp < 102) {   // h part
          float2 hv = *(const float2*)&sh_h[r][2*kp - 12];
          v = pkrtz(hv.x, hv.y);
        }
      }
      shA[r*GRUPU + kp] = v;
    }
    __syncthreads();

    // ---- GRU MFMA, one d-tile at a time (no spill) ----
    {
      const char* ahb = (const char*)shA + col*(GRUPU*4) + quad*16;
      #pragma unroll 1
      for (int i = 0; i < 3; ++i) {
        const int jR = wid*3 + i;
        const int jZ = 12 + wid*3 + i;
        const int jI = 24 + wid*3 + i;
        const int jH = 36 + wid*3 + i;
        f32x4 aR0 = (f32x4)0.f, aR1 = (f32x4)0.f;
        f32x4 aZ0 = (f32x4)0.f, aZ1 = (f32x4)0.f;
        f32x4 aI0 = (f32x4)0.f, aI1 = (f32x4)0.f;
        f32x4 aH0 = (f32x4)0.f, aH1 = (f32x4)0.f;
        #pragma unroll
        for (int kt = 0; kt < NKT; ++kt) {
          f16x8 ah0 = *(const f16x8*)(ahb + kt*64);
          f16x8 ah1 = *(const f16x8*)(ahb + 16*(GRUPU*4) + kt*64);
          f16x8 bR = *(const f16x8*)(Bh + (((size_t)(jR*NKT + kt)) << 9) + lane*8);
          f16x8 bZ = *(const f16x8*)(Bh + (((size_t)(jZ*NKT + kt)) << 9) + lane*8);
          f16x8 bH = *(const f16x8*)(Bh + (((size_t)(jH*NKT + kt)) << 9) + lane*8);
          aR0 = __builtin_amdgcn_mfma_f32_16x16x32_f16(ah0, bR, aR0, 0, 0, 0);
          aR1 = __builtin_amdgcn_mfma_f32_16x16x32_f16(ah1, bR, aR1, 0, 0, 0);
          aZ0 = __builtin_amdgcn_mfma_f32_16x16x32_f16(ah0, bZ, aZ0, 0, 0, 0);
          aZ1 = __builtin_amdgcn_mfma_f32_16x16x32_f16(ah1, bZ, aZ1, 0, 0, 0);
          aH0 = __builtin_amdgcn_mfma_f32_16x16x32_f16(ah0, bH, aH0, 0, 0, 0);
          aH1 = __builtin_amdgcn_mfma_f32_16x16x32_f16(ah1, bH, aH1, 0, 0, 0);
          if (kt == 0) {
            f16x8 bI = *(const f16x8*)(Bh + (((size_t)(jI*NKT)) << 9) + lane*8);
            aI0 = __builtin_amdgcn_mfma_f32_16x16x32_f16(ah0, bI, aI0, 0, 0, 0);
            aI1 = __builtin_amdgcn_mfma_f32_16x16x32_f16(ah1, bI, aI1, 0, 0, 0);
          }
        }
        const int d = (wid*3 + i)*16 + col;
        const float bR_ = bias768[d],       bZ_ = bias768[192 + d];
        const float bI_ = bias768[384 + d], bH_ = bias768[576 + d];
        #pragma unroll
        for (int q = 0; q < 4; ++q) {
          const int g0 = quad*4 + q;        // rows 0..15: always < ROWS
          float r_ = fsig(aR0[q] + bR_);
          float z_ = fsig(aZ0[q] + bZ_);
          float n_ = ftanh(aI0[q] + bI_ + r_*(aH0[q] + bH_));
          float hold = sh_h[g0][d];
          sh_h[g0][d] = (1.f - z_)*n_ + z_*hold;
        }
        #pragma unroll
        for (int q = 0; q < 4; ++q) {
          const int g1 = 16 + quad*4 + q;   // rows 16..31: guard < 30
          if (g1 < ROWS) {
            float r_ = fsig(aR1[q] + bR_);
            float z_ = fsig(aZ1[q] + bZ_);
            float n_ = ftanh(aI1[q] + bI_ + r_*(aH1[q] + bH_));
            float hold = sh_h[g1][d];
            sh_h[g1][d] = (1.f - z_)*n_ + z_*hold;
          }
        }
      }
    }
    __syncthreads();
  }

  // ---- conv: h-load + index math once per element, 6 FMAs inside ----
  {
    float acco[OO];
    #pragma unroll
    for (int o = 0; o < OO; ++o) acco[o] = 0.f;
    for (int u = tid; u < DD*TT*NN; u += 256) {
      int r = u % ROWS, c = u / ROWS;
      float hv = sh_h[r][c];
      #pragma unroll
      for (int o = 0; o < OO; ++o)
        acco[o] += conv1_w[o*(DD*TT*NN) + u] * hv;
    }
    #pragma unroll
    for (int o = 0; o < OO; ++o) {
      float v = acco[o];
      v += __shfl_xor(v, 1);  v += __shfl_xor(v, 2);  v += __shfl_xor(v, 4);
      v += __shfl_xor(v, 8);  v += __shfl_xor(v, 16); v += __shfl_xor(v, 32);
      acco[o] = v;
    }
    if (lane == 0) {
      #pragma unroll
      for (int o = 0; o < OO; ++o) red[wid][o] = acco[o];
    }
    __syncthreads();
    if (tid == 0) {
      float y[OO];
      #pragma unroll
      for (int o = 0; o < OO; ++o) {
        float s = conv1_b[o] + red[0][o] + red[1][o] + red[2][o] + red[3][o];
        y[o] = fmaxf(s, 0.f);
      }
      #pragma unroll
      for (int q = 0; q < OO; ++q) {
        float s = conv2_b[q];
        #pragma unroll
        for (int o = 0; o < OO; ++o) s += conv2_w[q*OO + o] * y[o];
        out[b*OO + q] = s;
      }
    }
  }
}

// ---------------------------------------------------------------- launch
extern "C" void kernel_launch(void* const* d_in, const int* in_sizes, int n_in,
                              void* d_out, int out_size, void* d_ws, size_t ws_size,
                              hipStream_t stream) {
  const float* node_resnet = (const float*)d_in[0];
  const float* pos      = (const float*)d_in[1];
  const int*   attmat   = (const int*)  d_in[2];
  const float* link_w1  = (const float*)d_in[3];
  const float* link_b1  = (const float*)d_in[4];
  const float* link_w2  = (const float*)d_in[5];
  const float* link_b2  = (const float*)d_in[6];
  const float* msg_Wh   = (const float*)d_in[7];
  const float* msg_We   = (const float*)d_in[8];
  const float* msg_b    = (const float*)d_in[9];
  const float* gru_Wih  = (const float*)d_in[10];
  const float* gru_Whh  = (const float*)d_in[11];
  const float* gru_bih  = (const float*)d_in[12];
  const float* gru_bhh  = (const float*)d_in[13];
  const float* conv1_w  = (const float*)d_in[14];
  const float* conv1_b  = (const float*)d_in[15];
  const float* conv2_w  = (const float*)d_in[16];
  const float* conv2_b  = (const float*)d_in[17];
  float* out = (float*)d_out;

  // ws layout: bias768 | Bh(fp16) | BLh(fp16)   (~0.4 MB)
  float* bias = (float*)d_ws;
  unsigned short* Bh  = (unsigned short*)(bias + GOUT);
  unsigned short* BLh = Bh + (size_t)NJT*NKT*512;

  k_pack<<<(NJT*NKT*512 + 255)/256, 256, 0, stream>>>(gru_Wih, gru_Whh,
      gru_bih, gru_bhh, Bh, bias);
  k_pack_link<<<(32*512 + 255)/256, 256, 0, stream>>>(link_w1, link_b1, BLh);
  k_fused<<<NB, 256, 0, stream>>>(node_resnet, pos, attmat,
      BLh, link_w2, link_b2,
      msg_Wh, msg_We, msg_b,
      Bh, bias,
      conv1_w, conv1_b, conv2_w, conv2_b, out);
}